// Round 13
// baseline (70.332 us; speedup 1.0000x reference)
//
#include <hip/hip_runtime.h>
#include <math.h>

// LinearGating: B=4,S=4096,D=2048,E=64,K=2 -> N=16384 rows
// out (flat f32): [weights N*64][indices N*2 (as float)][logits N*64][probs N*64]
//
// fp16 split-3 MFMA GEMM: C[N x 128] = X[N x 2048] @ [Wg|Wn]
//   x = h + d, w = H + D;  acc1 += h*H ; acc2 += h*(D*2^6) + (d*2^6)*H
//   C = acc1 + acc2 * 2^-6
// R13 = R12 with the schedule FIXED:
//  - B(31) tail DMA was missing (seg 31 computed with seg-29 weights)
//  - steady vmcnt must be 12 (= LOADA 4 + DMAB 8 younger than B(u)), was 20
//  - tail: B(30); vmcnt(8); C(29); lgkm(0); B(31); vmcnt(8); C(30); vmcnt(0); C(31)
// Structure: 2-wave blocks (128 thr), grid 512; waves own same 32 rows,
// disjoint K-halves, all 128 cols. B wave-private LDS via global_load_lds
// (own-wave counted vmcnt, NO barrier in k-loop). A in named regs, period-4.

typedef _Float16 f16;
typedef f16  f16x8  __attribute__((ext_vector_type(8)));
typedef float f32x16 __attribute__((ext_vector_type(16)));

constexpr int NROWS = 16384;
constexpr int DDIM  = 2048;
constexpr int NE    = 64;
constexpr int BM    = 32;
constexpr int KI    = 32;                 // k per iteration per wave
constexpr float NSCALE = 1.0f / 4096.0f;

__device__ __forceinline__ float softplus_f(float x) {
    return fmaxf(x, 0.0f) + log1pf(expf(-fabsf(x)));
}

__device__ __forceinline__ void gload_lds16(const void* g, void* l) {
    __builtin_amdgcn_global_load_lds(
        (const __attribute__((address_space(1))) void*)g,
        (__attribute__((address_space(3))) void*)l, 16, 0, 0);
}

// wave-local wait: NO s_barrier (waves independent in k-loop)
#define PIPE_WAIT(N) do {                                                  \
    asm volatile("s_waitcnt vmcnt(" #N ")" ::: "memory");                  \
    __builtin_amdgcn_sched_barrier(0);                                     \
} while (0)

// ---------------- W prep: fragment-ordered fp16 {H, D*2^6} ----------------
// blob(S 0..127, f 0..3, v 0..1): lane l, elem j = Wcat[S*16+(l>>5)*8+j][f*32+(l&31)]
__global__ __launch_bounds__(256) void wprep_kernel(
    const float* __restrict__ Wg, const float* __restrict__ Wn,
    f16* __restrict__ ws)
{
    int t = blockIdx.x * 256 + threadIdx.x;    // 0..32767
    int S = t >> 8;
    int f = (t >> 6) & 3;
    int l = t & 63;
    int k0  = S * 16 + (l >> 5) * 8;
    int col = f * 32 + (l & 31);
    const float* src = (col < NE) ? (Wg + col) : (Wn + col - NE);
    f16x8 hp, lp;
    #pragma unroll
    for (int j = 0; j < 8; ++j) {
        float w  = src[(size_t)(k0 + j) * NE];
        f16 h    = (f16)w;
        float hf = (float)h;
        hp[j] = h;
        lp[j] = (f16)((w - hf) * 64.0f);
    }
    size_t base = (size_t)(S * 4 + f) * 1024;   // f16 units
    *(f16x8*)(ws + base + l * 8)       = hp;
    *(f16x8*)(ws + base + 512 + l * 8) = lp;
}

// ---------------- main fused kernel ----------------
__global__ __launch_bounds__(128, 1) void gemm_gating(
    const float* __restrict__ x, const f16* __restrict__ wfrag,
    const float* __restrict__ noise,
    float* __restrict__ out_w, float* __restrict__ out_idx,
    float* __restrict__ out_logits, float* __restrict__ out_probs)
{
    __shared__ __align__(16) char smem[65536];   // 2 waves x (2 bufs x 16 KB)
    const int tid = threadIdx.x;
    const int l   = tid & 63;
    const int h   = tid >> 6;          // wave 0/1 = K-half
    const int row0 = blockIdx.x * BM;
    const int wbase = h * 32768;

    f32x16 acc1[4], acc2[4];
    #pragma unroll
    for (int c = 0; c < 4; ++c)
        #pragma unroll
        for (int r = 0; r < 16; ++r) { acc1[c][r] = 0.0f; acc2[c][r] = 0.0f; }

    // A: lane l row = l&31; k = h*1024 + t*32 + s*16 + (l>>5)*8 + {0..7}
    const float* aSrc = x + (size_t)(row0 + (l & 31)) * DDIM + h * 1024 + (l >> 5) * 8;
    const f16* bSrc = wfrag + l * 8;

#define LOADA(t, P) do {                                                    \
        const float* _p = aSrc + (size_t)(t) * KI;                          \
        P##00 = *(const float4*)(_p);                                       \
        P##01 = *(const float4*)(_p + 4);                                   \
        P##10 = *(const float4*)(_p + 16);                                  \
        P##11 = *(const float4*)(_p + 20);                                  \
    } while (0)

#define DMAB(t, buf) do {                                                   \
        int _S = h * 64 + (t) * 2;                                          \
        _Pragma("unroll")                                                   \
        for (int s = 0; s < 2; ++s)                                         \
            _Pragma("unroll")                                               \
            for (int c = 0; c < 4; ++c) {                                   \
                const f16* _src = bSrc + (size_t)((_S + s) * 4 + c) * 1024; \
                gload_lds16(_src,                                           \
                    smem + wbase + (buf) * 16384 + ((s * 2 + 0) * 4 + c) * 1024); \
                gload_lds16(_src + 512,                                     \
                    smem + wbase + (buf) * 16384 + ((s * 2 + 1) * 4 + c) * 1024); \
            }                                                               \
    } while (0)

#define CVT8(F0, F1, AH, AL) do {                                           \
        float _xs[8] = {F0.x, F0.y, F0.z, F0.w, F1.x, F1.y, F1.z, F1.w};    \
        _Pragma("unroll")                                                   \
        for (int j = 0; j < 8; ++j) {                                       \
            f16 _hh = (f16)_xs[j];                                          \
            AH[j] = _hh;                                                    \
            AL[j] = (f16)((_xs[j] - (float)_hh) * 64.0f);                   \
        }                                                                   \
    } while (0)

#define COMPUTE(buf, P) do {                                                \
        f16x8 _Ah, _Al, _Bh, _Bl;                                           \
        CVT8(P##00, P##01, _Ah, _Al);                                       \
        __builtin_amdgcn_s_setprio(1);                                      \
        _Pragma("unroll")                                                   \
        for (int c = 0; c < 4; ++c) {                                       \
            _Bh = *(const f16x8*)(smem + wbase + (buf) * 16384 + (0 * 4 + c) * 1024 + l * 16); \
            _Bl = *(const f16x8*)(smem + wbase + (buf) * 16384 + (1 * 4 + c) * 1024 + l * 16); \
            acc1[c] = __builtin_amdgcn_mfma_f32_32x32x16_f16(_Ah, _Bh, acc1[c], 0, 0, 0); \
            acc2[c] = __builtin_amdgcn_mfma_f32_32x32x16_f16(_Ah, _Bl, acc2[c], 0, 0, 0); \
            acc2[c] = __builtin_amdgcn_mfma_f32_32x32x16_f16(_Al, _Bh, acc2[c], 0, 0, 0); \
        }                                                                   \
        __builtin_amdgcn_s_setprio(0);                                      \
        CVT8(P##10, P##11, _Ah, _Al);                                       \
        __builtin_amdgcn_s_setprio(1);                                      \
        _Pragma("unroll")                                                   \
        for (int c = 0; c < 4; ++c) {                                       \
            _Bh = *(const f16x8*)(smem + wbase + (buf) * 16384 + (2 * 4 + c) * 1024 + l * 16); \
            _Bl = *(const f16x8*)(smem + wbase + (buf) * 16384 + (3 * 4 + c) * 1024 + l * 16); \
            acc1[c] = __builtin_amdgcn_mfma_f32_32x32x16_f16(_Ah, _Bh, acc1[c], 0, 0, 0); \
            acc2[c] = __builtin_amdgcn_mfma_f32_32x32x16_f16(_Ah, _Bl, acc2[c], 0, 0, 0); \
            acc2[c] = __builtin_amdgcn_mfma_f32_32x32x16_f16(_Al, _Bh, acc2[c], 0, 0, 0); \
        }                                                                   \
        __builtin_amdgcn_s_setprio(0);                                      \
    } while (0)

    float4 A000, A001, A010, A011;
    float4 A100, A101, A110, A111;
    float4 A200, A201, A210, A211;
    float4 A300, A301, A310, A311;

    // -------- prologue: B(0) + A(0..2) = 20 outstanding --------
    DMAB(0, 0);
    LOADA(0, A0); LOADA(1, A1); LOADA(2, A2);

    // t = 0: younger-than-B(0) = A(0..3) 16 + B(1) 8 = 24
    LOADA(3, A3); DMAB(1, 1); PIPE_WAIT(24); COMPUTE(0, A0);

    // steady: segments 1..28, period 4. Younger-than-B(u) = A(u+3) 4 + B(u+1) 8 = 12
    for (int t = 1; t < 29; t += 4) {
        LOADA(t + 3, A0); DMAB(t + 1, 0); PIPE_WAIT(12); COMPUTE(1, A1);
        LOADA(t + 4, A1); DMAB(t + 2, 1); PIPE_WAIT(12); COMPUTE(0, A2);
        LOADA(t + 5, A2); DMAB(t + 3, 0); PIPE_WAIT(12); COMPUTE(1, A3);
        LOADA(t + 6, A3); DMAB(t + 4, 1); PIPE_WAIT(12); COMPUTE(0, A0);
    }
    // tails: segments 29, 30, 31
    DMAB(30, 0); PIPE_WAIT(8); COMPUTE(1, A1);              // seg 29 (buf1)
    asm volatile("s_waitcnt lgkmcnt(0)" ::: "memory");       // buf1 reads drained
    __builtin_amdgcn_sched_barrier(0);
    DMAB(31, 1); PIPE_WAIT(8); COMPUTE(0, A2);              // seg 30 (buf0)
    PIPE_WAIT(0); COMPUTE(1, A3);                            // seg 31 (buf1)
#undef LOADA
#undef DMAB
#undef CVT8
#undef COMPUTE

    __syncthreads();   // both waves done

    // ---- merge K-halves ----
    float* mg = (float*)(smem + 32768);    // [32][128]
    if (h == 1) {
        #pragma unroll
        for (int c = 0; c < 4; ++c)
            #pragma unroll
            for (int r = 0; r < 16; ++r) {
                float cv = fmaf(acc2[c][r], 0.015625f, acc1[c][r]);
                int row = (r & 3) + 8 * (r >> 2) + 4 * (l >> 5);
                int col = c * 32 + (l & 31);
                mg[row * 128 + col] = cv;
            }
    }
    __syncthreads();

    float* lgf = (float*)smem;             // [32][132]
    if (h == 0) {
        #pragma unroll
        for (int c = 0; c < 4; ++c)
            #pragma unroll
            for (int r = 0; r < 16; ++r) {
                float cv = fmaf(acc2[c][r], 0.015625f, acc1[c][r]);
                int row = (r & 3) + 8 * (r >> 2) + 4 * (l >> 5);
                int col = c * 32 + (l & 31);
                lgf[row * 132 + col] = cv + mg[row * 128 + col];
            }
    }
    __syncthreads();

    // ---- phase1: noise injection; 128 thr = 32 rows x 4 chunks of 16 ----
    {
        const int pr  = tid & 31;          // row
        const int c16 = tid >> 5;          // chunk of 16 experts (0..3)
        const int n1  = row0 + pr;
        #pragma unroll
        for (int q = 0; q < 4; ++q) {
            float4 G  = *(const float4*)(lgf + pr * 132 + c16 * 16 + q * 4);
            float4 NL = *(const float4*)(lgf + pr * 132 + 64 + c16 * 16 + q * 4);
            float4 NZ = *(const float4*)(noise + (size_t)n1 * NE + c16 * 16 + q * 4);
            G.x += NZ.x * softplus_f(NL.x) * NSCALE;
            G.y += NZ.y * softplus_f(NL.y) * NSCALE;
            G.z += NZ.z * softplus_f(NL.z) * NSCALE;
            G.w += NZ.w * softplus_f(NL.w) * NSCALE;
            *(float4*)(lgf + pr * 132 + c16 * 16 + q * 4) = G;
            *(float4*)(out_logits + (size_t)n1 * NE + c16 * 16 + q * 4) = G;
        }
    }
    __syncthreads();

    // ---- phase2: per-row top-2 + softmax; 4 lanes/row x 32 rows ----
    {
        const int g2   = l >> 2;           // row within wave's 16-row group
        const int c    = l & 3;            // expert chunk of 16
        const int row2 = h * 16 + g2;
        const int n2   = row0 + row2;

        float mv[16];
        {
            const float4* mr = (const float4*)(lgf + row2 * 132 + c * 16);
            #pragma unroll
            for (int q = 0; q < 4; ++q) {
                float4 v = mr[q];
                mv[q*4+0] = v.x; mv[q*4+1] = v.y; mv[q*4+2] = v.z; mv[q*4+3] = v.w;
            }
        }
        float v0 = -INFINITY, v1 = -INFINITY;
        int i0 = 0, i1 = 0;
        #pragma unroll
        for (int j = 0; j < 16; ++j) {
            float v = mv[j]; int e = c * 16 + j;
            if (v > v0) { v1 = v0; i1 = i0; v0 = v; i0 = e; }
            else if (v > v1) { v1 = v; i1 = e; }
        }
        #pragma unroll
        for (int m = 1; m <= 2; m <<= 1) {
            float ov0 = __shfl_xor(v0, m), ov1 = __shfl_xor(v1, m);
            int   oi0 = __shfl_xor(i0, m), oi1 = __shfl_xor(i1, m);
            if (ov0 > v0) {
                bool keep = (v0 > ov1);
                v1 = keep ? v0 : ov1; i1 = keep ? i0 : oi1;
                v0 = ov0; i0 = oi0;
            } else if (ov0 > v1) {
                v1 = ov0; i1 = oi0;
            }
        }
        const int srcl = l & 60;
        v0 = __shfl(v0, srcl); i0 = __shfl(i0, srcl);
        v1 = __shfl(v1, srcl); i1 = __shfl(i1, srcl);

        float se = 0.0f;
        #pragma unroll
        for (int j = 0; j < 16; ++j) se += expf(mv[j] - v0);
        se += __shfl_xor(se, 1); se += __shfl_xor(se, 2);
        float inv_se = 1.0f / se;

        float t  = expf(v1 - v0);
        float w0 = 1.0f / (1.0f + t);
        float w1 = t * w0;

        float pr[16], wt[16];
        #pragma unroll
        for (int j = 0; j < 16; ++j) {
            int e = c * 16 + j;
            pr[j] = expf(mv[j] - v0) * inv_se;
            wt[j] = (e == i0) ? w0 : ((e == i1) ? w1 : 0.0f);
        }
        #pragma unroll
        for (int q = 0; q < 4; ++q) {
            *(float4*)(out_probs + (size_t)n2 * NE + c * 16 + q * 4) =
                make_float4(pr[q*4+0], pr[q*4+1], pr[q*4+2], pr[q*4+3]);
            *(float4*)(out_w + (size_t)n2 * NE + c * 16 + q * 4) =
                make_float4(wt[q*4+0], wt[q*4+1], wt[q*4+2], wt[q*4+3]);
        }
        if (c == 0) {
            *(float2*)(out_idx + (size_t)n2 * 2) = make_float2((float)i0, (float)i1);
        }
    }
}

extern "C" void kernel_launch(void* const* d_in, const int* in_sizes, int n_in,
                              void* d_out, int out_size, void* d_ws, size_t ws_size,
                              hipStream_t stream) {
    (void)in_sizes; (void)n_in; (void)ws_size; (void)out_size;
    const float* x     = (const float*)d_in[0];
    const float* Wg    = (const float*)d_in[1];
    const float* Wn    = (const float*)d_in[2];
    const float* noise = (const float*)d_in[3];
    float* out        = (float*)d_out;
    float* out_w      = out;
    float* out_idx    = out + (size_t)NROWS * NE;
    float* out_logits = out_idx + (size_t)NROWS * 2;
    float* out_probs  = out_logits + (size_t)NROWS * NE;
    f16* wfrag = (f16*)d_ws;   // 1 MB

    wprep_kernel<<<128, 256, 0, stream>>>(Wg, Wn, wfrag);
    gemm_gating<<<NROWS / BM, 128, 0, stream>>>(
        x, wfrag, noise, out_w, out_idx, out_logits, out_probs);
}

// Round 14
// 68.262 us; speedup vs baseline: 1.0303x; 1.0303x over previous
//
#include <hip/hip_runtime.h>
#include <math.h>

// LinearGating: B=4,S=4096,D=2048,E=64,K=2 -> N=16384 rows
// out (flat f32): [weights N*64][indices N*2 (as float)][logits N*64][probs N*64]
//
// fp16 split-3 MFMA GEMM: C[N x 128] = X[N x 2048] @ [Wg|Wn]
//   x = h + d, w = H + D;  acc1 += h*H ; acc2 += h*(D*2^6) + (d*2^6)*H
//   C = acc1 + acc2 * 2^-6
// R14: BM=64, 1024 threads (16 waves = 2kh x 2rg x 4cq), grid 256 (1 block/CU,
// 4 waves/SIMD). B staged ONCE per block, shared by both row-groups -> B L2
// traffic halves (512->256 MB). All-DMA staging (A raw f32 + B f16 = 48 KB/seg),
// TRIPLE buffer, stage-2-ahead, ONE barrier/seg, uniform vmcnt(3) (every wave
// issues exactly 3 DMAs/seg, after the barrier). Split-3 cvt in compute.

typedef _Float16 f16;
typedef f16  f16x8  __attribute__((ext_vector_type(8)));
typedef float f32x16 __attribute__((ext_vector_type(16)));

constexpr int NROWS = 16384;
constexpr int DDIM  = 2048;
constexpr int NE    = 64;
constexpr int BM    = 64;
constexpr int NITER = 32;            // segs of 32k per K-half (K=1024 each)
constexpr int BUFSZ = 49152;         // 16 KB A + 32 KB B per seg
constexpr float NSCALE = 1.0f / 4096.0f;

__device__ __forceinline__ float softplus_f(float x) {
    return fmaxf(x, 0.0f) + log1pf(expf(-fabsf(x)));
}

__device__ __forceinline__ void gload_lds16(const void* g, void* l) {
    __builtin_amdgcn_global_load_lds(
        (const __attribute__((address_space(1))) void*)g,
        (__attribute__((address_space(3))) void*)l, 16, 0, 0);
}

#define PIPE_BAR(N) do {                                                   \
    asm volatile("s_waitcnt vmcnt(" #N ") lgkmcnt(0)" ::: "memory");       \
    __builtin_amdgcn_sched_barrier(0);                                     \
    __builtin_amdgcn_s_barrier();                                          \
    __builtin_amdgcn_sched_barrier(0);                                     \
} while (0)

// ---------------- W prep: fragment-ordered fp16 {H, D*2^6} ----------------
// blob(S 0..127, f 0..3, v 0..1): lane l, elem j = Wcat[S*16+(l>>5)*8+j][f*32+(l&31)]
__global__ __launch_bounds__(256) void wprep_kernel(
    const float* __restrict__ Wg, const float* __restrict__ Wn,
    f16* __restrict__ ws)
{
    int t = blockIdx.x * 256 + threadIdx.x;    // 0..32767
    int S = t >> 8;
    int f = (t >> 6) & 3;
    int l = t & 63;
    int k0  = S * 16 + (l >> 5) * 8;
    int col = f * 32 + (l & 31);
    const float* src = (col < NE) ? (Wg + col) : (Wn + col - NE);
    f16x8 hp, lp;
    #pragma unroll
    for (int j = 0; j < 8; ++j) {
        float w  = src[(size_t)(k0 + j) * NE];
        f16 h    = (f16)w;
        float hf = (float)h;
        hp[j] = h;
        lp[j] = (f16)((w - hf) * 64.0f);
    }
    size_t base = (size_t)(S * 4 + f) * 1024;   // f16 units
    *(f16x8*)(ws + base + l * 8)       = hp;
    *(f16x8*)(ws + base + 512 + l * 8) = lp;
}

// ---------------- main fused kernel ----------------
__global__ __launch_bounds__(1024, 1) void gemm_gating(
    const float* __restrict__ x, const f16* __restrict__ wfrag,
    const float* __restrict__ noise,
    float* __restrict__ out_w, float* __restrict__ out_idx,
    float* __restrict__ out_logits, float* __restrict__ out_probs)
{
    __shared__ __align__(16) char smem[147456];   // 3 x 48 KB
    const int tid = threadIdx.x;
    const int l   = tid & 63;
    const int w   = tid >> 6;        // 0..15
    const int kh  = w >> 3;          // K-half
    const int rg  = (w >> 2) & 1;    // row group (32 rows)
    const int cq  = w & 3;           // col quad (32 cols)
    const int row0 = blockIdx.x * BM;

    f32x16 acc1, acc2;
    #pragma unroll
    for (int r = 0; r < 16; ++r) { acc1[r] = 0.0f; acc2[r] = 0.0f; }

    // ---- per-wave DMA descriptors: 3 units of 1 KB per seg ----
    // units 0..15  = A[kh][rg][S][half]: 32 rows x (4 f32 per lane)
    //   lane l src: x[row0 + rg*32 + (l&31)][kh*1024 + t*32 + S*16 + (l>>5)*8 + half*4]
    // units 16..47 = B[kh][f][v][S]: wfrag blob(kh*64 + t*2 + S, f) half v
    const char* dsrc[3];
    int dstr[3], doff[3];
    #pragma unroll
    for (int j = 0; j < 3; ++j) {
        int u = w * 3 + j;
        if (u < 16) {
            int akh = u >> 3, arg = (u >> 2) & 1, aS = (u >> 1) & 1, ah = u & 1;
            dsrc[j] = (const char*)(x + (size_t)(row0 + arg * 32 + (l & 31)) * DDIM
                                      + akh * 1024 + aS * 16 + (l >> 5) * 8 + ah * 4);
            dstr[j] = 32 * 4;            // t*32 floats
            doff[j] = u * 1024;
        } else {
            int b = u - 16;
            int bS = b & 1, bv = (b >> 1) & 1, bf = (b >> 2) & 3, bkh = b >> 4;
            dsrc[j] = (const char*)(wfrag + (size_t)((bkh * 64 + bS) * 4 + bf) * 1024
                                          + bv * 512 + l * 8);
            dstr[j] = 16384;             // t*2 blobs of 4 KB... = 2*4*1024 f16 = 16 KB
            doff[j] = 16384 + b * 1024;
        }
    }
    auto stage = [&](int t, int buf) {
        #pragma unroll
        for (int j = 0; j < 3; ++j)
            gload_lds16(dsrc[j] + (size_t)t * dstr[j], smem + buf * BUFSZ + doff[j]);
    };

    // fragment LDS offsets for this wave
    const int aoff0 = ((((kh * 2 + rg) * 2 + 0) * 2 + 0)) * 1024;  // S=0
    const int boffH = 16384 + (((kh * 4 + cq) * 2 + 0) * 2) * 1024;
    const int boffL = 16384 + (((kh * 4 + cq) * 2 + 1) * 2) * 1024;

    auto compute = [&](int buf) {
        const char* bb = smem + buf * BUFSZ;
        #pragma unroll
        for (int S = 0; S < 2; ++S) {
            float4 a0 = *(const float4*)(bb + aoff0 + S * 2048 + l * 16);
            float4 a1 = *(const float4*)(bb + aoff0 + S * 2048 + 1024 + l * 16);
            float xs[8] = {a0.x, a0.y, a0.z, a0.w, a1.x, a1.y, a1.z, a1.w};
            f16x8 Ah, Al;
            #pragma unroll
            for (int j = 0; j < 8; ++j) {
                f16 hh   = (f16)xs[j];
                float hf = (float)hh;
                Ah[j] = hh;
                Al[j] = (f16)((xs[j] - hf) * 64.0f);
            }
            f16x8 Bh = *(const f16x8*)(bb + boffH + S * 1024 + l * 16);
            f16x8 Bl = *(const f16x8*)(bb + boffL + S * 1024 + l * 16);
            __builtin_amdgcn_s_setprio(1);
            acc1 = __builtin_amdgcn_mfma_f32_32x32x16_f16(Ah, Bh, acc1, 0, 0, 0);
            acc2 = __builtin_amdgcn_mfma_f32_32x32x16_f16(Ah, Bl, acc2, 0, 0, 0);
            acc2 = __builtin_amdgcn_mfma_f32_32x32x16_f16(Al, Bh, acc2, 0, 0, 0);
            __builtin_amdgcn_s_setprio(0);
        }
    };

    // -------- prologue: stage segs 0,1 (6 DMAs outstanding) --------
    stage(0, 0);
    stage(1, 1);

    // -------- main loop: one barrier/seg, uniform vmcnt --------
    for (int t = 0; t < 30; ++t) {
        PIPE_BAR(3);                 // seg t landed (t+1's 3 still in flight)
        stage(t + 2, (t + 2) % 3);   // into buf read at t-1 (drained by lgkmcnt(0))
        compute(t % 3);
    }
    PIPE_BAR(3);  compute(0);        // seg 30 (buf 30%3=0); seg31 in flight
    PIPE_BAR(0);  compute(1);        // seg 31 (buf 1)
    __syncthreads();

    // ---- merge K-halves: kh=1 waves write partials, kh=0 adds ----
    float* mg = (float*)smem;              // [64][128]
    if (kh == 1) {
        #pragma unroll
        for (int r = 0; r < 16; ++r) {
            float cv = fmaf(acc2[r], 0.015625f, acc1[r]);
            int row = rg * 32 + (r & 3) + 8 * (r >> 2) + 4 * (l >> 5);
            int col = cq * 32 + (l & 31);
            mg[row * 128 + col] = cv;
        }
    }
    __syncthreads();

    float* lgf = (float*)(smem + 32768);   // [64][132]
    if (kh == 0) {
        #pragma unroll
        for (int r = 0; r < 16; ++r) {
            float cv = fmaf(acc2[r], 0.015625f, acc1[r]);
            int row = rg * 32 + (r & 3) + 8 * (r >> 2) + 4 * (l >> 5);
            int col = cq * 32 + (l & 31);
            lgf[row * 132 + col] = cv + mg[row * 128 + col];
        }
    }
    __syncthreads();

    // ---- phase1: noise injection; 1024 thr = 64 rows x 16 float4-chunks ----
    {
        const int pr = tid & 63;           // row
        const int c4 = tid >> 6;           // float4 chunk 0..15
        const int n1 = row0 + pr;
        float4 G  = *(const float4*)(lgf + pr * 132 + c4 * 4);
        float4 NL = *(const float4*)(lgf + pr * 132 + 64 + c4 * 4);
        float4 NZ = *(const float4*)(noise + (size_t)n1 * NE + c4 * 4);
        G.x += NZ.x * softplus_f(NL.x) * NSCALE;
        G.y += NZ.y * softplus_f(NL.y) * NSCALE;
        G.z += NZ.z * softplus_f(NL.z) * NSCALE;
        G.w += NZ.w * softplus_f(NL.w) * NSCALE;
        *(float4*)(lgf + pr * 132 + c4 * 4) = G;
        *(float4*)(out_logits + (size_t)n1 * NE + c4 * 4) = G;
    }
    __syncthreads();

    // ---- phase2: per-row top-2 + softmax; waves 0..7, 8 lanes/row ----
    if (w < 8) {
        const int g2   = l >> 3;           // row within wave's 8-row group
        const int c    = l & 7;            // expert chunk of 8
        const int row2 = w * 8 + g2;
        const int n2   = row0 + row2;

        float mv[8];
        {
            const float4* mr = (const float4*)(lgf + row2 * 132 + c * 8);
            float4 m0 = mr[0], m1 = mr[1];
            mv[0]=m0.x; mv[1]=m0.y; mv[2]=m0.z; mv[3]=m0.w;
            mv[4]=m1.x; mv[5]=m1.y; mv[6]=m1.z; mv[7]=m1.w;
        }
        float v0 = -INFINITY, v1 = -INFINITY;
        int i0 = 0, i1 = 0;
        #pragma unroll
        for (int j = 0; j < 8; ++j) {
            float v = mv[j]; int e = c * 8 + j;
            if (v > v0) { v1 = v0; i1 = i0; v0 = v; i0 = e; }
            else if (v > v1) { v1 = v; i1 = e; }
        }
        #pragma unroll
        for (int m = 1; m <= 4; m <<= 1) {
            float ov0 = __shfl_xor(v0, m), ov1 = __shfl_xor(v1, m);
            int   oi0 = __shfl_xor(i0, m), oi1 = __shfl_xor(i1, m);
            if (ov0 > v0) {
                bool keep = (v0 > ov1);
                v1 = keep ? v0 : ov1; i1 = keep ? i0 : oi1;
                v0 = ov0; i0 = oi0;
            } else if (ov0 > v1) {
                v1 = ov0; i1 = oi0;
            }
        }
        const int srcl = l & 56;
        v0 = __shfl(v0, srcl); i0 = __shfl(i0, srcl);
        v1 = __shfl(v1, srcl); i1 = __shfl(i1, srcl);

        float se = 0.0f;
        #pragma unroll
        for (int j = 0; j < 8; ++j) se += expf(mv[j] - v0);
        se += __shfl_xor(se, 1); se += __shfl_xor(se, 2); se += __shfl_xor(se, 4);
        float inv_se = 1.0f / se;

        float t  = expf(v1 - v0);
        float w0 = 1.0f / (1.0f + t);
        float w1 = t * w0;

        float pr[8], wt[8];
        #pragma unroll
        for (int j = 0; j < 8; ++j) {
            int e = c * 8 + j;
            pr[j] = expf(mv[j] - v0) * inv_se;
            wt[j] = (e == i0) ? w0 : ((e == i1) ? w1 : 0.0f);
        }
        *(float4*)(out_probs + (size_t)n2 * NE + c * 8)     = make_float4(pr[0], pr[1], pr[2], pr[3]);
        *(float4*)(out_probs + (size_t)n2 * NE + c * 8 + 4) = make_float4(pr[4], pr[5], pr[6], pr[7]);
        *(float4*)(out_w + (size_t)n2 * NE + c * 8)         = make_float4(wt[0], wt[1], wt[2], wt[3]);
        *(float4*)(out_w + (size_t)n2 * NE + c * 8 + 4)     = make_float4(wt[4], wt[5], wt[6], wt[7]);
        if (c == 0) {
            *(float2*)(out_idx + (size_t)n2 * 2) = make_float2((float)i0, (float)i1);
        }
    }
}

extern "C" void kernel_launch(void* const* d_in, const int* in_sizes, int n_in,
                              void* d_out, int out_size, void* d_ws, size_t ws_size,
                              hipStream_t stream) {
    (void)in_sizes; (void)n_in; (void)ws_size; (void)out_size;
    const float* x     = (const float*)d_in[0];
    const float* Wg    = (const float*)d_in[1];
    const float* Wn    = (const float*)d_in[2];
    const float* noise = (const float*)d_in[3];
    float* out        = (float*)d_out;
    float* out_w      = out;
    float* out_idx    = out + (size_t)NROWS * NE;
    float* out_logits = out_idx + (size_t)NROWS * 2;
    float* out_probs  = out_logits + (size_t)NROWS * NE;
    f16* wfrag = (f16*)d_ws;   // 1 MB

    wprep_kernel<<<128, 256, 0, stream>>>(Wg, Wn, wfrag);
    gemm_gating<<<NROWS / BM, 1024, 0, stream>>>(
        x, wfrag, noise, out_w, out_idx, out_logits, out_probs);
}

// Round 15
// 52.525 us; speedup vs baseline: 1.3390x; 1.2996x over previous
//
#include <hip/hip_runtime.h>
#include <math.h>

// LinearGating: B=4,S=4096,D=2048,E=64,K=2 -> N=16384 rows
// out (flat f32): [weights N*64][indices N*2 (as float)][logits N*64][probs N*64]
//
// fp16 split-3 MFMA GEMM: C[N x 128] = X[N x 2048] @ [Wg|Wn]
//   x = h + d, w = H + D;  acc1 += h*H ; acc2 += h*(D*2^6) + (d*2^6)*H
//   C = acc1 + acc2 * 2^-6
// R15 = R10 structure, UNPINNED (m141 lesson): no inline asm, no
// sched_barrier, plain __syncthreads (no global_load_lds anywhere -> the
// compiler emits counted vmcnt at uses, only lgkmcnt(0) at barriers).
// A: f32->reg depth-4 (4 named slots), convert once in staging, ds_write
// f16 blobs (4 LDS bufs). B: f16 blobs->reg depth-2 (2 named sets, reload
// immediately after consumption). Loop unrolled x4: all indices static.

typedef _Float16 f16;
typedef f16  f16x4  __attribute__((ext_vector_type(4)));
typedef f16  f16x8  __attribute__((ext_vector_type(8)));
typedef float f32x16 __attribute__((ext_vector_type(16)));

constexpr int NROWS = 16384;
constexpr int DDIM  = 2048;
constexpr int NE    = 64;
constexpr int BM    = 32;
constexpr int KI    = 32;                 // k per segment per half
constexpr float NSCALE = 1.0f / 4096.0f;

// LDS: A f16 blobs [0,32K): buf(4) x half(2) x s(2) x v(2) x 1KB
//      merge mg [32K,48K); lgf reuses [0,16896) after k-loop
__device__ __forceinline__ int a_off(int buf, int h, int s, int v) {
    return (((buf * 2 + h) * 2 + s) * 2 + v) * 1024;
}

__device__ __forceinline__ float softplus_f(float x) {
    return fmaxf(x, 0.0f) + log1pf(expf(-fabsf(x)));
}

// ---------------- W prep: fragment-ordered fp16 {H, D*2^6} ----------------
// blob(S 0..127, f 0..3, v 0..1): lane l, elem j = Wcat[S*16+(l>>5)*8+j][f*32+(l&31)]
__global__ __launch_bounds__(256) void wprep_kernel(
    const float* __restrict__ Wg, const float* __restrict__ Wn,
    f16* __restrict__ ws)
{
    int t = blockIdx.x * 256 + threadIdx.x;    // 0..32767
    int S = t >> 8;
    int f = (t >> 6) & 3;
    int l = t & 63;
    int k0  = S * 16 + (l >> 5) * 8;
    int col = f * 32 + (l & 31);
    const float* src = (col < NE) ? (Wg + col) : (Wn + col - NE);
    f16x8 hp, lp;
    #pragma unroll
    for (int j = 0; j < 8; ++j) {
        float w  = src[(size_t)(k0 + j) * NE];
        f16 h    = (f16)w;
        float hf = (float)h;
        hp[j] = h;
        lp[j] = (f16)((w - hf) * 64.0f);
    }
    size_t base = (size_t)(S * 4 + f) * 1024;   // f16 units
    *(f16x8*)(ws + base + l * 8)       = hp;
    *(f16x8*)(ws + base + 512 + l * 8) = lp;
}

// ---------------- main fused kernel ----------------
__global__ __launch_bounds__(512, 4) void gemm_gating(
    const float* __restrict__ x, const f16* __restrict__ wfrag,
    const float* __restrict__ noise,
    float* __restrict__ out_w, float* __restrict__ out_idx,
    float* __restrict__ out_logits, float* __restrict__ out_probs)
{
    __shared__ __align__(16) char smem[49152];
    const int tid = threadIdx.x;
    const int l   = tid & 63;
    const int w   = tid >> 6;      // 0..7
    const int h   = w >> 2;        // compute: k-half
    const int f   = w & 3;         // compute: col quad (cols f*32..+31)
    const int row0 = blockIdx.x * BM;

    f32x16 acc1, acc2;
    #pragma unroll
    for (int r = 0; r < 16; ++r) { acc1[r] = 0.0f; acc2[r] = 0.0f; }

    // --- A staging role: wave w owns (h_s = w>>2, s_s = (w>>1)&1, j4 = w&1) ---
    const int h_s = w >> 2, s_s = (w >> 1) & 1, j4 = w & 1;
    const float* aSrc = x + (size_t)(row0 + (l & 31)) * DDIM
                          + h_s * 1024 + s_s * 16 + (l >> 5) * 8 + j4 * 4;
    auto loadA = [&](int t) -> float4 {
        return *(const float4*)(aSrc + (size_t)t * KI);
    };
    auto cvtWrite = [&](float4 xv, int buf) {   // buf is compile-time static
        float xs[4] = {xv.x, xv.y, xv.z, xv.w};
        f16x4 hi, lo;
        #pragma unroll
        for (int j = 0; j < 4; ++j) {
            f16 hh   = (f16)xs[j];
            float hf = (float)hh;
            hi[j] = hh;
            lo[j] = (f16)((xs[j] - hf) * 64.0f);
        }
        *(f16x4*)(smem + a_off(buf, h_s, s_s, 0) + l * 16 + j4 * 8) = hi;
        *(f16x4*)(smem + a_off(buf, h_s, s_s, 1) + l * 16 + j4 * 8) = lo;
    };

    // --- B: wave-private, global->reg. Slice S = h*64 + t*2 + s ---
    const f16* bBase = wfrag + (size_t)f * 1024 + l * 8;
#define LOADB(t, H0, L0, H1, L1) do {                                       \
        const f16* _p = bBase + (size_t)(h * 64 + (t) * 2) * 4096;          \
        H0 = *(const f16x8*)_p;          L0 = *(const f16x8*)(_p + 512);    \
        H1 = *(const f16x8*)(_p + 4096); L1 = *(const f16x8*)(_p + 4608);   \
    } while (0)

    auto compute = [&](int buf, f16x8 Bh0, f16x8 Bl0, f16x8 Bh1, f16x8 Bl1) {
        #pragma unroll
        for (int s = 0; s < 2; ++s) {
            f16x8 Ah = *(const f16x8*)(smem + a_off(buf, h, s, 0) + l * 16);
            f16x8 Al = *(const f16x8*)(smem + a_off(buf, h, s, 1) + l * 16);
            f16x8 Bh = s ? Bh1 : Bh0;
            f16x8 Bl = s ? Bl1 : Bl0;
            acc1 = __builtin_amdgcn_mfma_f32_32x32x16_f16(Ah, Bh, acc1, 0, 0, 0);
            acc2 = __builtin_amdgcn_mfma_f32_32x32x16_f16(Ah, Bl, acc2, 0, 0, 0);
            acc2 = __builtin_amdgcn_mfma_f32_32x32x16_f16(Al, Bh, acc2, 0, 0, 0);
        }
    };

    float4 a0, a1, a2, a3;
    f16x8 b0h0, b0l0, b0h1, b0l1;   // B set 0 (even segs)
    f16x8 b1h0, b1l0, b1h1, b1l1;   // B set 1 (odd segs)

    // -------- prologue: A(0..3) regs, B(0),B(1) regs, bufs 0,1 written --------
    a0 = loadA(0); a1 = loadA(1); a2 = loadA(2); a3 = loadA(3);
    LOADB(0, b0h0, b0l0, b0h1, b0l1);
    LOADB(1, b1h0, b1l0, b1h1, b1l1);
    cvtWrite(a0, 0);
    cvtWrite(a1, 1);
    __syncthreads();

    // -------- main loop: 8 trips x 4 segs, all indices static --------
    for (int tb = 0; tb < 32; tb += 4) {
        // seg tb+0: buf0, Bset0
        compute(0, b0h0, b0l0, b0h1, b0l1);
        if (tb + 4 < 32) a0 = loadA(tb + 4);
        if (tb + 2 < 32) LOADB(tb + 2, b0h0, b0l0, b0h1, b0l1);
        cvtWrite(a2, 2);                       // seg tb+2 -> buf2
        __syncthreads();
        // seg tb+1: buf1, Bset1
        compute(1, b1h0, b1l0, b1h1, b1l1);
        if (tb + 5 < 32) a1 = loadA(tb + 5);
        if (tb + 3 < 32) LOADB(tb + 3, b1h0, b1l0, b1h1, b1l1);
        cvtWrite(a3, 3);                       // seg tb+3 -> buf3
        __syncthreads();
        // seg tb+2: buf2, Bset0
        compute(2, b0h0, b0l0, b0h1, b0l1);
        if (tb + 6 < 32) a2 = loadA(tb + 6);
        if (tb + 4 < 32) {
            LOADB(tb + 4, b0h0, b0l0, b0h1, b0l1);
            cvtWrite(a0, 0);                   // seg tb+4 -> buf0
        }
        __syncthreads();
        // seg tb+3: buf3, Bset1
        compute(3, b1h0, b1l0, b1h1, b1l1);
        if (tb + 7 < 32) a3 = loadA(tb + 7);
        if (tb + 5 < 32) {
            LOADB(tb + 5, b1h0, b1l0, b1h1, b1l1);
            cvtWrite(a1, 1);                   // seg tb+5 -> buf1
        }
        __syncthreads();
    }
#undef LOADB

    // ---- merge K-halves: h=1 waves write partial, h=0 adds ----
    float* mg = (float*)(smem + 32768);    // [32][128]
    if (h == 1) {
        #pragma unroll
        for (int r = 0; r < 16; ++r) {
            float cv = fmaf(acc2[r], 0.015625f, acc1[r]);
            int row = (r & 3) + 8 * (r >> 2) + 4 * (l >> 5);
            int col = f * 32 + (l & 31);
            mg[row * 128 + col] = cv;
        }
    }
    __syncthreads();

    float* lgf = (float*)smem;             // [32][132]
    if (h == 0) {
        #pragma unroll
        for (int r = 0; r < 16; ++r) {
            float cv = fmaf(acc2[r], 0.015625f, acc1[r]);
            int row = (r & 3) + 8 * (r >> 2) + 4 * (l >> 5);
            int col = f * 32 + (l & 31);
            lgf[row * 132 + col] = cv + mg[row * 128 + col];
        }
    }
    __syncthreads();

    // ---- phase1: noise injection; 512 thr = 32 rows x 16 float4-chunks ----
    {
        const int pr = tid & 31;           // row
        const int c4 = tid >> 5;           // float4 chunk 0..15
        const int n1 = row0 + pr;
        float4 G  = *(const float4*)(lgf + pr * 132 + c4 * 4);
        float4 NL = *(const float4*)(lgf + pr * 132 + 64 + c4 * 4);
        float4 NZ = *(const float4*)(noise + (size_t)n1 * NE + c4 * 4);
        G.x += NZ.x * softplus_f(NL.x) * NSCALE;
        G.y += NZ.y * softplus_f(NL.y) * NSCALE;
        G.z += NZ.z * softplus_f(NL.z) * NSCALE;
        G.w += NZ.w * softplus_f(NL.w) * NSCALE;
        *(float4*)(lgf + pr * 132 + c4 * 4) = G;
        *(float4*)(out_logits + (size_t)n1 * NE + c4 * 4) = G;
    }
    __syncthreads();

    // ---- phase2: per-row top-2 + softmax; waves 0..3, 8 lanes/row ----
    if (w < 4) {
        const int g2   = l >> 3;           // row within wave's 8-row group
        const int c    = l & 7;            // expert chunk of 8
        const int row2 = w * 8 + g2;
        const int n2   = row0 + row2;

        float mv[8];
        {
            const float4* mr = (const float4*)(lgf + row2 * 132 + c * 8);
            float4 m0 = mr[0], m1 = mr[1];
            mv[0]=m0.x; mv[1]=m0.y; mv[2]=m0.z; mv[3]=m0.w;
            mv[4]=m1.x; mv[5]=m1.y; mv[6]=m1.z; mv[7]=m1.w;
        }
        float v0 = -INFINITY, v1 = -INFINITY;
        int i0 = 0, i1 = 0;
        #pragma unroll
        for (int j = 0; j < 8; ++j) {
            float v = mv[j]; int e = c * 8 + j;
            if (v > v0) { v1 = v0; i1 = i0; v0 = v; i0 = e; }
            else if (v > v1) { v1 = v; i1 = e; }
        }
        #pragma unroll
        for (int m = 1; m <= 4; m <<= 1) {
            float ov0 = __shfl_xor(v0, m), ov1 = __shfl_xor(v1, m);
            int   oi0 = __shfl_xor(i0, m), oi1 = __shfl_xor(i1, m);
            if (ov0 > v0) {
                bool keep = (v0 > ov1);
                v1 = keep ? v0 : ov1; i1 = keep ? i0 : oi1;
                v0 = ov0; i0 = oi0;
            } else if (ov0 > v1) {
                v1 = ov0; i1 = oi0;
            }
        }
        const int srcl = l & 56;
        v0 = __shfl(v0, srcl); i0 = __shfl(i0, srcl);
        v1 = __shfl(v1, srcl); i1 = __shfl(i1, srcl);

        float se = 0.0f;
        #pragma unroll
        for (int j = 0; j < 8; ++j) se += expf(mv[j] - v0);
        se += __shfl_xor(se, 1); se += __shfl_xor(se, 2); se += __shfl_xor(se, 4);
        float inv_se = 1.0f / se;

        float t  = expf(v1 - v0);
        float w0 = 1.0f / (1.0f + t);
        float w1 = t * w0;

        float pr[8], wt[8];
        #pragma unroll
        for (int j = 0; j < 8; ++j) {
            int e = c * 8 + j;
            pr[j] = expf(mv[j] - v0) * inv_se;
            wt[j] = (e == i0) ? w0 : ((e == i1) ? w1 : 0.0f);
        }
        *(float4*)(out_probs + (size_t)n2 * NE + c * 8)     = make_float4(pr[0], pr[1], pr[2], pr[3]);
        *(float4*)(out_probs + (size_t)n2 * NE + c * 8 + 4) = make_float4(pr[4], pr[5], pr[6], pr[7]);
        *(float4*)(out_w + (size_t)n2 * NE + c * 8)         = make_float4(wt[0], wt[1], wt[2], wt[3]);
        *(float4*)(out_w + (size_t)n2 * NE + c * 8 + 4)     = make_float4(wt[4], wt[5], wt[6], wt[7]);
        if (c == 0) {
            *(float2*)(out_idx + (size_t)n2 * 2) = make_float2((float)i0, (float)i1);
        }
    }
}

extern "C" void kernel_launch(void* const* d_in, const int* in_sizes, int n_in,
                              void* d_out, int out_size, void* d_ws, size_t ws_size,
                              hipStream_t stream) {
    (void)in_sizes; (void)n_in; (void)ws_size; (void)out_size;
    const float* x     = (const float*)d_in[0];
    const float* Wg    = (const float*)d_in[1];
    const float* Wn    = (const float*)d_in[2];
    const float* noise = (const float*)d_in[3];
    float* out        = (float*)d_out;
    float* out_w      = out;
    float* out_idx    = out + (size_t)NROWS * NE;
    float* out_logits = out_idx + (size_t)NROWS * 2;
    float* out_probs  = out_logits + (size_t)NROWS * NE;
    f16* wfrag = (f16*)d_ws;   // 1 MB

    wprep_kernel<<<128, 256, 0, stream>>>(Wg, Wn, wfrag);
    gemm_gating<<<NROWS / BM, 512, 0, stream>>>(
        x, wfrag, noise, out_w, out_idx, out_logits, out_probs);
}